// Round 9
// baseline (331.817 us; speedup 1.0000x reference)
//
#include <hip/hip_runtime.h>
#include <hip/hip_bf16.h>
#include <math.h>

#define N_TOK 4096
#define DM 512
#define FDIM 128
#define G 8
#define FG 16
#define DH 128
#define DE 256
#define ES 4
#define E_EXP 32
#define LN_EPS 1e-5f
#define BT 32   // expert token tile (MFMA)

typedef __attribute__((ext_vector_type(8))) short bf16x8;  // 8 bf16 = 4 VGPRs
typedef __attribute__((ext_vector_type(4))) float f32x4;

#define MFMA16(a, b, c) __builtin_amdgcn_mfma_f32_16x16x32_bf16((a), (b), (c), 0, 0, 0)

__device__ __forceinline__ float gelu_t(float x) {
    const float c = 0.7978845608028654f; // sqrt(2/pi)
    float x3 = x * x * x;
    return 0.5f * x * (1.0f + tanhf(c * (x + 0.044715f * x3)));
}

__device__ __forceinline__ short f2bf(float f) {
    __hip_bfloat16 h = __float2bfloat16(f);
    return *reinterpret_cast<short*>(&h);
}
__device__ __forceinline__ float bf2f(short s) {
    __hip_bfloat16 h = *reinterpret_cast<__hip_bfloat16*>(&s);
    return __bfloat162float(h);
}
// exact 3-way split: x == bf2f(h)+bf2f(m)+bf2f(l) bit-exactly for fp32 x
__device__ __forceinline__ void split3(float x, short& h, short& m, short& l) {
    h = f2bf(x);
    float r = x - bf2f(h);   // exact in fp32
    m = f2bf(r);
    float r2 = r - bf2f(m);  // exact; <=6 significant bits remain
    l = f2bf(r2);            // exact
}

// ---------------- weight conversion block body (shared by k_pre and k_enc_all) ----------------
struct ConvJob { const float* src; short* dh; short* dm; short* dl;
                 int KB, NB, Kreal, plain, blk0; };
struct ConvJobs { ConvJob j[10]; };
struct ConvJobs2 { ConvJob j[2]; };

__device__ __forceinline__ void conv_block(const ConvJob jb, int rel) {
    int mat = rel / jb.KB, kb = rel % jb.KB;
    int ncols = jb.NB * 16;
    const float* s = jb.src + (size_t)mat * jb.Kreal * ncols;
    size_t dbase = ((size_t)mat * jb.KB + kb) * jb.NB * 512;
    for (int p = threadIdx.x; p < jb.NB * 64; p += 256) {
        int nb = p >> 6, lane = p & 63;
        int row0 = kb * 32 + ((lane >> 4) << 3);
        int col = nb * 16 + (lane & 15);
        if (jb.plain) {
            union { short sh[8]; uint4 v; } t;
#pragma unroll
            for (int j = 0; j < 8; j++) {
                float x = (row0 + j < jb.Kreal) ? s[(size_t)(row0 + j) * ncols + col] : 0.f;
                t.sh[j] = f2bf(x);
            }
            *(uint4*)&jb.dh[dbase + (size_t)p * 8] = t.v;
        } else {
            union { short sh[8]; uint4 v; } hi, mi, lo;
#pragma unroll
            for (int j = 0; j < 8; j++) {
                float x = (row0 + j < jb.Kreal) ? s[(size_t)(row0 + j) * ncols + col] : 0.f;
                split3(x, hi.sh[j], mi.sh[j], lo.sh[j]);
            }
            *(uint4*)&jb.dh[dbase + (size_t)p * 8] = hi.v;
            *(uint4*)&jb.dm[dbase + (size_t)p * 8] = mi.v;
            *(uint4*)&jb.dl[dbase + (size_t)p * 8] = lo.v;
        }
    }
}

// ---------------- fused pre-pass: small weight-conversion jobs + LN(hidden) ----------------
__global__ void k_pre(ConvJobs J, int nconv,
                      const float* __restrict__ hidden,
                      const float* __restrict__ pg, const float* __restrict__ pb,
                      const float* __restrict__ rg, const float* __restrict__ rb,
                      __hip_bfloat16* __restrict__ h_normb, float* __restrict__ hL) {
    int b = blockIdx.x;
    if (b >= nconv) {
        // -------- LN of hidden: pre_ln -> h_norm (bf16) and rh_ln -> hL (fp32) --------
        int n = b - nconv;
        int j = threadIdx.x; // 0..255
        const float* x = hidden + (size_t)n * DM;
        float v0 = x[j], v1 = x[j + 256];
        float s = v0 + v1, q = v0 * v0 + v1 * v1;
#pragma unroll
        for (int o = 32; o; o >>= 1) { s += __shfl_down(s, o); q += __shfl_down(q, o); }
        __shared__ float red[8];
        int w = j >> 6;
        if ((j & 63) == 0) { red[w] = s; red[4 + w] = q; }
        __syncthreads();
        float sum = red[0] + red[1] + red[2] + red[3];
        float sq  = red[4] + red[5] + red[6] + red[7];
        float m = sum * (1.0f / DM);
        float var = sq * (1.0f / DM) - m * m;
        float rs = rsqrtf(var + LN_EPS);
        float t0 = (v0 - m) * rs, t1 = (v1 - m) * rs;
        size_t base = (size_t)n * DM;
        h_normb[base + j]       = __float2bfloat16(t0 * pg[j]       + pb[j]);
        h_normb[base + j + 256] = __float2bfloat16(t1 * pg[j + 256] + pb[j + 256]);
        hL[base + j]           = t0 * rg[j]       + rb[j];
        hL[base + j + 256]     = t1 * rg[j + 256] + rb[j + 256];
        return;
    }
    int ji = 0;
#pragma unroll
    for (int i = 1; i < 10; i++) if (b >= J.j[i].blk0) ji = i;
    conv_block(J.j[ji], b - J.j[ji].blk0);
}

// ---------------- 2-layer MLP body via 3-split MFMA: Y = gelu(LN?(X)@W1+b1)@W2+b2 ----------------
template <int KB_TOT, bool DO_LN>
__device__ __forceinline__ void enc2_body(
        int bx, char* smem,
        const float* __restrict__ X,
        const float* __restrict__ lng, const float* __restrict__ lnb,
        const short* __restrict__ W1h, const short* __restrict__ W1m, const short* __restrict__ W1l,
        const float* __restrict__ B1,
        const short* __restrict__ W2h, const short* __restrict__ W2m, const short* __restrict__ W2l,
        const float* __restrict__ B2,
        float* __restrict__ Y) {
    constexpr int K = KB_TOT * 32;
    const int n0 = bx * 32;
    const int tid = threadIdx.x;
    const int wave = tid >> 6, lane = tid & 63;
    const int quad = lane >> 4, lm = lane & 15;
    const int mt = wave & 1;
    const int ngb = (wave >> 1) * 4;   // 4 n-tiles per wave

    short (*Ah)[132] = (short(*)[132])smem;
    short (*Am)[132] = (short(*)[132])(smem + 32 * 132 * 2);
    short (*Al)[132] = (short(*)[132])(smem + 2 * 32 * 132 * 2);

    f32x4 acc[4];
#pragma unroll
    for (int i = 0; i < 4; i++) acc[i] = (f32x4)(0.f);

    if (DO_LN) {
        for (int idx = tid; idx < 1024; idx += 256) {
            int row = idx >> 5, c4 = (idx & 31) * 4;
            float4 v = *(const float4*)&X[(size_t)(n0 + row) * K + c4];
            float s = v.x + v.y + v.z + v.w;
            float q = v.x * v.x + v.y * v.y + v.z * v.z + v.w * v.w;
#pragma unroll
            for (int o = 16; o; o >>= 1) { s += __shfl_xor(s, o); q += __shfl_xor(q, o); }
            float mean = s * (1.0f / 128.0f);
            float var = q * (1.0f / 128.0f) - mean * mean;
            float rs = rsqrtf(var + LN_EPS);
            float xv[4] = {(v.x - mean) * rs * lng[c4 + 0] + lnb[c4 + 0],
                           (v.y - mean) * rs * lng[c4 + 1] + lnb[c4 + 1],
                           (v.z - mean) * rs * lng[c4 + 2] + lnb[c4 + 2],
                           (v.w - mean) * rs * lng[c4 + 3] + lnb[c4 + 3]};
#pragma unroll
            for (int j = 0; j < 4; j++) {
                short h, m, l; split3(xv[j], h, m, l);
                Ah[row][c4 + j] = h; Am[row][c4 + j] = m; Al[row][c4 + j] = l;
            }
        }
        __syncthreads();
#pragma unroll
        for (int kb = 0; kb < KB_TOT; kb++) {
            bf16x8 ah = *(const bf16x8*)&Ah[mt * 16 + lm][kb * 32 + quad * 8];
            bf16x8 am = *(const bf16x8*)&Am[mt * 16 + lm][kb * 32 + quad * 8];
            bf16x8 al = *(const bf16x8*)&Al[mt * 16 + lm][kb * 32 + quad * 8];
#pragma unroll
            for (int nt = 0; nt < 4; nt++) {
                size_t bi = (((size_t)kb * 8 + ngb + nt) * 64 + lane) * 8;
                bf16x8 bh = *(const bf16x8*)&W1h[bi];
                bf16x8 bm = *(const bf16x8*)&W1m[bi];
                bf16x8 bl = *(const bf16x8*)&W1l[bi];
                acc[nt] = MFMA16(al, bh, acc[nt]);
                acc[nt] = MFMA16(am, bm, acc[nt]);
                acc[nt] = MFMA16(ah, bl, acc[nt]);
                acc[nt] = MFMA16(am, bh, acc[nt]);
                acc[nt] = MFMA16(ah, bm, acc[nt]);
                acc[nt] = MFMA16(ah, bh, acc[nt]);
            }
        }
    } else {
        for (int kb = 0; kb < KB_TOT; kb++) {
            const float* xs = X + (size_t)(n0 + mt * 16 + lm) * K + kb * 32 + quad * 8;
            float4 x0 = *(const float4*)xs, x1 = *(const float4*)(xs + 4);
            float xv[8] = {x0.x, x0.y, x0.z, x0.w, x1.x, x1.y, x1.z, x1.w};
            bf16x8 ah, am, al;
#pragma unroll
            for (int j = 0; j < 8; j++) {
                short h, m, l; split3(xv[j], h, m, l);
                ah[j] = h; am[j] = m; al[j] = l;
            }
#pragma unroll
            for (int nt = 0; nt < 4; nt++) {
                size_t bi = (((size_t)kb * 8 + ngb + nt) * 64 + lane) * 8;
                bf16x8 bh = *(const bf16x8*)&W1h[bi];
                bf16x8 bm = *(const bf16x8*)&W1m[bi];
                bf16x8 bl = *(const bf16x8*)&W1l[bi];
                acc[nt] = MFMA16(al, bh, acc[nt]);
                acc[nt] = MFMA16(am, bm, acc[nt]);
                acc[nt] = MFMA16(ah, bl, acc[nt]);
                acc[nt] = MFMA16(am, bh, acc[nt]);
                acc[nt] = MFMA16(ah, bm, acc[nt]);
                acc[nt] = MFMA16(ah, bh, acc[nt]);
            }
        }
    }
    __syncthreads();
#pragma unroll
    for (int nt = 0; nt < 4; nt++) {
        int col = (ngb + nt) * 16 + lm;
        float b1 = B1[col];
#pragma unroll
        for (int r = 0; r < 4; r++) {
            int row = mt * 16 + quad * 4 + r;
            short h, m, l; split3(gelu_t(acc[nt][r] + b1), h, m, l);
            Ah[row][col] = h; Am[row][col] = m; Al[row][col] = l;
        }
    }
    __syncthreads();
    f32x4 acc2[4];
#pragma unroll
    for (int i = 0; i < 4; i++) acc2[i] = (f32x4)(0.f);
#pragma unroll
    for (int kb = 0; kb < 4; kb++) {
        bf16x8 ah = *(const bf16x8*)&Ah[mt * 16 + lm][kb * 32 + quad * 8];
        bf16x8 am = *(const bf16x8*)&Am[mt * 16 + lm][kb * 32 + quad * 8];
        bf16x8 al = *(const bf16x8*)&Al[mt * 16 + lm][kb * 32 + quad * 8];
#pragma unroll
        for (int nt = 0; nt < 4; nt++) {
            size_t bi = (((size_t)kb * 8 + ngb + nt) * 64 + lane) * 8;
            bf16x8 bh = *(const bf16x8*)&W2h[bi];
            bf16x8 bm = *(const bf16x8*)&W2m[bi];
            bf16x8 bl = *(const bf16x8*)&W2l[bi];
            acc2[nt] = MFMA16(al, bh, acc2[nt]);
            acc2[nt] = MFMA16(am, bm, acc2[nt]);
            acc2[nt] = MFMA16(ah, bl, acc2[nt]);
            acc2[nt] = MFMA16(am, bh, acc2[nt]);
            acc2[nt] = MFMA16(ah, bm, acc2[nt]);
            acc2[nt] = MFMA16(ah, bh, acc2[nt]);
        }
    }
#pragma unroll
    for (int nt = 0; nt < 4; nt++) {
        int col = (ngb + nt) * 16 + lm;
        float b2 = B2[col];
#pragma unroll
        for (int r = 0; r < 4; r++) {
            int row = mt * 16 + quad * 4 + r;
            Y[(size_t)(n0 + row) * DH + col] = acc2[nt][r] + b2;
        }
    }
}

// ---------------- single-group encoder body: one (32-token tile, group) per block ----------------
__device__ __forceinline__ void genc_one(
        int bx, int g, char* smem,
        const float* __restrict__ feat,
        const float* __restrict__ gln_g, const float* __restrict__ gln_b,
        const short* __restrict__ W1h, const short* __restrict__ W1m, const short* __restrict__ W1l,
        const float* __restrict__ gb1,
        const short* __restrict__ W2h, const short* __restrict__ W2m, const short* __restrict__ W2l,
        const float* __restrict__ gb2,
        float* __restrict__ g_enc) {
    const int tid = threadIdx.x;
    const int wave = tid >> 6, lane = tid & 63;
    const int quad = lane >> 4, lm = lane & 15;
    const int mt = wave & 1;
    const int ngb = (wave >> 1) * 4;
    const int n0 = bx * 32;

    short (*Ah)[132] = (short(*)[132])smem;
    short (*Am)[132] = (short(*)[132])(smem + 8448);
    short (*Al)[132] = (short(*)[132])(smem + 2 * 8448);

    {
        int t = tid >> 3, sub = tid & 7;
        const float* fr = feat + (size_t)(n0 + t) * FDIM + g * FG;
        float xv[FG];
        float mean = 0.f;
#pragma unroll
        for (int i = 0; i < FG; i++) { xv[i] = fr[i]; mean += xv[i]; }
        mean *= (1.0f / FG);
        float var = 0.f;
#pragma unroll
        for (int i = 0; i < FG; i++) { float d = xv[i] - mean; var += d * d; }
        var *= (1.0f / FG);
        float rs = rsqrtf(var + LN_EPS);
#pragma unroll
        for (int j = 0; j < 2; j++) {
            int i = sub * 2 + j;
            float xn = (xv[i] - mean) * rs * gln_g[g * FG + i] + gln_b[g * FG + i];
            short h, m, l; split3(xn, h, m, l);
            Ah[t][i] = h; Am[t][i] = m; Al[t][i] = l;
            Ah[t][16 + i] = 0; Am[t][16 + i] = 0; Al[t][16 + i] = 0;  // K pad to 32
        }
    }
    __syncthreads();
    f32x4 acc[4];
#pragma unroll
    for (int i = 0; i < 4; i++) acc[i] = (f32x4)(0.f);
    {
        bf16x8 ah = *(const bf16x8*)&Ah[mt * 16 + lm][quad * 8];
        bf16x8 am = *(const bf16x8*)&Am[mt * 16 + lm][quad * 8];
        bf16x8 al = *(const bf16x8*)&Al[mt * 16 + lm][quad * 8];
#pragma unroll
        for (int nt = 0; nt < 4; nt++) {
            size_t bi = (((size_t)g * 8 + ngb + nt) * 64 + lane) * 8;  // KB=1 per mat
            bf16x8 bh = *(const bf16x8*)&W1h[bi];
            bf16x8 bm = *(const bf16x8*)&W1m[bi];
            bf16x8 bl = *(const bf16x8*)&W1l[bi];
            acc[nt] = MFMA16(al, bh, acc[nt]);
            acc[nt] = MFMA16(am, bm, acc[nt]);
            acc[nt] = MFMA16(ah, bl, acc[nt]);
            acc[nt] = MFMA16(am, bh, acc[nt]);
            acc[nt] = MFMA16(ah, bm, acc[nt]);
            acc[nt] = MFMA16(ah, bh, acc[nt]);
        }
    }
    __syncthreads();
#pragma unroll
    for (int nt = 0; nt < 4; nt++) {
        int col = (ngb + nt) * 16 + lm;
        float b1 = gb1[g * DH + col];
#pragma unroll
        for (int r = 0; r < 4; r++) {
            int row = mt * 16 + quad * 4 + r;
            short h, m, l; split3(gelu_t(acc[nt][r] + b1), h, m, l);
            Ah[row][col] = h; Am[row][col] = m; Al[row][col] = l;
        }
    }
    __syncthreads();
    f32x4 acc2[4];
#pragma unroll
    for (int i = 0; i < 4; i++) acc2[i] = (f32x4)(0.f);
#pragma unroll
    for (int kb = 0; kb < 4; kb++) {
        bf16x8 a2h = *(const bf16x8*)&Ah[mt * 16 + lm][kb * 32 + quad * 8];
        bf16x8 a2m = *(const bf16x8*)&Am[mt * 16 + lm][kb * 32 + quad * 8];
        bf16x8 a2l = *(const bf16x8*)&Al[mt * 16 + lm][kb * 32 + quad * 8];
#pragma unroll
        for (int nt = 0; nt < 4; nt++) {
            size_t bi = ((((size_t)g * 4 + kb) * 8 + ngb + nt) * 64 + lane) * 8;
            bf16x8 bh = *(const bf16x8*)&W2h[bi];
            bf16x8 bm = *(const bf16x8*)&W2m[bi];
            bf16x8 bl = *(const bf16x8*)&W2l[bi];
            acc2[nt] = MFMA16(a2l, bh, acc2[nt]);
            acc2[nt] = MFMA16(a2m, bm, acc2[nt]);
            acc2[nt] = MFMA16(a2h, bl, acc2[nt]);
            acc2[nt] = MFMA16(a2m, bh, acc2[nt]);
            acc2[nt] = MFMA16(a2h, bm, acc2[nt]);
            acc2[nt] = MFMA16(a2h, bh, acc2[nt]);
        }
    }
#pragma unroll
    for (int nt = 0; nt < 4; nt++) {
        int col = (ngb + nt) * 16 + lm;
        float b2 = gb2[g * DH + col];
#pragma unroll
        for (int r = 0; r < 4; r++) {
            int row = mt * 16 + quad * 4 + r;
            g_enc[((size_t)(n0 + row) * G + g) * DH + col] = acc2[nt][r] + b2;
        }
    }
}

// ---------------- fused encoder launch: exconv(768) + rh(128) + sf(128) + genc(1024) ----------------
// Expert-weight conversion blocks (bids 0..767) are only needed before k_expert (3 launches
// later) -- folding them here takes them off the serial critical path and overlaps their
// memory traffic with the VALU/MFMA-bound encoder blocks.
__global__ __launch_bounds__(256) void k_enc_all(
        ConvJobs2 JE,
        const float* __restrict__ hL, const float* __restrict__ feat,
        const float* __restrict__ sf_g, const float* __restrict__ sf_b,
        const float* __restrict__ gln_g, const float* __restrict__ gln_b,
        const short* Brh1H, const short* Brh1M, const short* Brh1L, const float* rh_b1,
        const short* Brh2H, const short* Brh2M, const short* Brh2L, const float* rh_b2,
        const short* Bsf1H, const short* Bsf1M, const short* Bsf1L, const float* sf_b1,
        const short* Bsf2H, const short* Bsf2M, const short* Bsf2L, const float* sf_b2,
        const short* Bgf1H, const short* Bgf1M, const short* Bgf1L, const float* gf_b1,
        const short* Bgf2H, const short* Bgf2M, const short* Bgf2L, const float* gf_b2,
        float* __restrict__ h_enc, float* __restrict__ s_enc, float* __restrict__ g_enc) {
    __shared__ __align__(16) char smem[3 * 8448];   // 25.3 KB -> 6 blocks/CU
    int bid = blockIdx.x;
    if (bid < 768) {
        const ConvJob jb = (bid < JE.j[1].blk0) ? JE.j[0] : JE.j[1];
        conv_block(jb, bid - jb.blk0);
        return;
    }
    int b2 = bid - 768;
    if (b2 < 128)
        enc2_body<16, false>(b2, smem, hL, nullptr, nullptr,
                             Brh1H, Brh1M, Brh1L, rh_b1, Brh2H, Brh2M, Brh2L, rh_b2, h_enc);
    else if (b2 < 256)
        enc2_body<4, true>(b2 - 128, smem, feat, sf_g, sf_b,
                           Bsf1H, Bsf1M, Bsf1L, sf_b1, Bsf2H, Bsf2M, Bsf2L, sf_b2, s_enc);
    else {
        int idx = b2 - 256;    // (idx & 7) = group -> XCD affinity for gf weights
        genc_one(idx >> 3, idx & 7, smem, feat, gln_g, gln_b,
                 Bgf1H, Bgf1M, Bgf1L, gf_b1, Bgf2H, Bgf2M, Bgf2L, gf_b2, g_enc);
    }
}

// ---------------- MFMA router v4 (round-0 verbatim): 64 tokens x 1 group, 8 waves ----------------
// Serial epilogue kept intentionally: this exact body compiles to VGPR 64 -> 3 blocks/CU ->
// 54us; every variant (incl. parallel epilogue) pushed VGPR to 120 -> 2 blocks/CU -> 75-105us.
// DO NOT TOUCH.
__global__ __launch_bounds__(512) void k_router_mfma(
        const float* __restrict__ h_enc, const float* __restrict__ s_enc,
        const float* __restrict__ g_enc,
        const short* __restrict__ BpgH, const short* __restrict__ BpgM, const short* __restrict__ BpgL,
        const short* __restrict__ BirH, const short* __restrict__ BirM, const short* __restrict__ BirL,
        const float* __restrict__ pb1, const float* __restrict__ pw2, const float* __restrict__ pb2,
        const float* __restrict__ ib1, const float* __restrict__ iw2, const float* __restrict__ ib2,
        float* __restrict__ glog, float* __restrict__ ilog) {
    const int g = blockIdx.x & 7;       // group -> XCD affinity for B + g_enc
    const int bx = blockIdx.x >> 3;     // 64-token tile (0..63)
    const int n0 = bx * 64;
    const int tid = threadIdx.x;
    const int wave = tid >> 6, lane = tid & 63;
    const int quad = lane >> 4, lm = lane & 15;
    const bool is_pg = wave < 4;
    const int nbase = (wave & 3) * 2;   // 2 n-tiles per wave, 4 waves cover 8
    const short* Bh = is_pg ? BpgH : (BirH + (size_t)g * 65536);
    const short* Bm = is_pg ? BpgM : (BirM + (size_t)g * 65536);
    const short* Bl = is_pg ? BpgL : (BirL + (size_t)g * 65536);

    // LDS: A staging for one 4-kb chunk: [split 3][kbl 4][t16 4][lane 64][8 shorts] = 48 KB.
    // Epilogue (2 x 32x129 fp32 = 33 KB) aliases it after the K-loop.
    __shared__ __align__(16) char smem[49152];

    f32x4 acc[4][2];
#pragma unroll
    for (int mt = 0; mt < 4; mt++)
#pragma unroll
        for (int nt = 0; nt < 2; nt++) acc[mt][nt] = (f32x4)(0.f);

    for (int ch = 0; ch < 4; ch++) {
        __syncthreads();   // previous chunk's LDS reads complete
        // stage chunk: items = (kbl, t16, lane2); split3 from raw encoder fp32
        for (int idx = tid; idx < 1024; idx += 512) {
            int kbl = idx >> 8, rem = idx & 255;
            int t16 = rem >> 6, lane2 = rem & 63;
            int gkb = ch * 4 + kbl;
            size_t loff = (size_t)kbl * 4096 + t16 * 1024 + (size_t)lane2 * 16;
            int n = n0 + t16 * 16 + (lane2 & 15);
            int csub = (lane2 >> 4) * 8;
            float xv[8];
            if (gkb < 8) {
                // k in [0,256) = [h_enc | s_enc]
                int c0 = gkb * 32 + csub;
                const float* src = (c0 < 128) ? (h_enc + (size_t)n * DH + c0)
                                              : (s_enc + (size_t)n * DH + (c0 - 128));
                float4 x0 = *(const float4*)src, x1 = *(const float4*)(src + 4);
                xv[0]=x0.x; xv[1]=x0.y; xv[2]=x0.z; xv[3]=x0.w;
                xv[4]=x1.x; xv[5]=x1.y; xv[6]=x1.z; xv[7]=x1.w;
            } else {
                // k in [256,512) = [g_enc | h_enc*g_enc]
                int c0 = (gkb - 8) * 32 + csub;
                if (c0 < 128) {
                    const float* gs = g_enc + ((size_t)n * G + g) * DH + c0;
                    float4 x0 = *(const float4*)gs, x1 = *(const float4*)(gs + 4);
                    xv[0]=x0.x; xv[1]=x0.y; xv[2]=x0.z; xv[3]=x0.w;
                    xv[4]=x1.x; xv[5]=x1.y; xv[6]=x1.z; xv[7]=x1.w;
                } else {
                    int c = c0 - 128;
                    const float* gs = g_enc + ((size_t)n * G + g) * DH + c;
                    const float* hsrc = h_enc + (size_t)n * DH + c;
                    float4 g0 = *(const float4*)gs, g1 = *(const float4*)(gs + 4);
                    float4 h0 = *(const float4*)hsrc, h1 = *(const float4*)(hsrc + 4);
                    xv[0]=h0.x*g0.x; xv[1]=h0.y*g0.y; xv[2]=h0.z*g0.z; xv[3]=h0.w*g0.w;
                    xv[4]=h1.x*g1.x; xv[5]=h1.y*g1.y; xv[6]=h1.z*g1.z; xv[7]=h1.w*g1.w;
                }
            }
            union { short sh[8]; uint4 v; } hi, mi, lo;
#pragma unroll
            for (int j = 0; j < 8; j++) split3(xv[j], hi.sh[j], mi.sh[j], lo.sh[j]);
            *(uint4*)(smem + loff)         = hi.v;
            *(uint4*)(smem + 16384 + loff) = mi.v;
            *(uint4*)(smem + 32768 + loff) = lo.v;
        }
        __syncthreads();
        // compute chunk
#pragma unroll
        for (int kbl = 0; kbl < 4; kbl++) {
            int kb = ch * 4 + kbl;
            bf16x8 Ahf[4], Amf[4], Alf[4];
#pragma unroll
            for (int mt = 0; mt < 4; mt++) {
                size_t loff = (size_t)kbl * 4096 + mt * 1024 + (size_t)lane * 16;
                Ahf[mt] = *(const bf16x8*)(smem + loff);
                Amf[mt] = *(const bf16x8*)(smem + 16384 + loff);
                Alf[mt] = *(const bf16x8*)(smem + 32768 + loff);
            }
#pragma unroll
            for (int nt = 0; nt < 2; nt++) {
                int nb = nbase + nt;
                size_t bi = (((size_t)kb * 8 + nb) * 64 + lane) * 8;
                bf16x8 bh = *(const bf16x8*)&Bh[bi];
                bf16x8 bm = *(const bf16x8*)&Bm[bi];
                bf16x8 bl = *(const bf16x8*)&Bl[bi];
#pragma unroll
                for (int mt = 0; mt < 4; mt++) {
                    acc[mt][nt] = MFMA16(Alf[mt], bh, acc[mt][nt]);
                    acc[mt][nt] = MFMA16(Amf[mt], bm, acc[mt][nt]);
                    acc[mt][nt] = MFMA16(Ahf[mt], bl, acc[mt][nt]);
                    acc[mt][nt] = MFMA16(Amf[mt], bh, acc[mt][nt]);
                    acc[mt][nt] = MFMA16(Ahf[mt], bm, acc[mt][nt]);
                    acc[mt][nt] = MFMA16(Ahf[mt], bh, acc[mt][nt]);
                }
            }
        }
    }

    // epilogue: two 32-row halves reusing staging LDS (ph 32x129 + ih 32x129 = 33 KB)
    float (*ph)[129] = (float(*)[129])smem;
    float (*ih)[129] = (float(*)[129])(smem + 32 * 129 * 4);
    for (int h = 0; h < 2; h++) {
        __syncthreads();   // h=0: K-loop LDS reads done; h=1: prev half's logit reads done
#pragma unroll
        for (int mi = 0; mi < 2; mi++) {
            int mt = 2 * h + mi;
#pragma unroll
            for (int nt = 0; nt < 2; nt++) {
                int col = (nbase + nt) * 16 + lm;
                float b1 = is_pg ? pb1[col] : ib1[g * DH + col];
                float* dst = is_pg ? &ph[0][0] : &ih[0][0];
#pragma unroll
                for (int r = 0; r < 4; r++) {
                    int row = mi * 16 + quad * 4 + r;
                    dst[row * 129 + col] = gelu_t(acc[mt][nt][r] + b1);
                }
            }
        }
        __syncthreads();
        if (tid < 32) {
            float s = pb2[0];
            for (int i = 0; i < DH; i++) s += ph[tid][i] * pw2[i];
            glog[(size_t)(n0 + h * 32 + tid) * G + g] = s; // TEMP = 1.0
        } else if (tid >= 128 && tid < 256) {
            int t = (tid - 128) >> 2, e = (tid - 128) & 3;
            float s = ib2[g * ES + e];
            const float* w = iw2 + (size_t)g * DH * ES;
            for (int i = 0; i < DH; i++) s += ih[t][i] * w[i * ES + e];
            ilog[((size_t)(n0 + h * 32 + t) * G + g) * ES + e] = s;
        }
    }
}

// ---------------- top-k softmax + dispatch to per-expert lists ----------------
__global__ void k_topk(const float* __restrict__ glog, const float* __restrict__ ilog,
                       int* __restrict__ cnt, int* __restrict__ toks, float* __restrict__ wgts) {
    int n = blockIdx.x * blockDim.x + threadIdx.x;
    if (n >= N_TOK) return;
    float gl[G];
#pragma unroll
    for (int g = 0; g < G; g++) gl[g] = glog[(size_t)n * G + g];
    int i1 = 0; float v1 = gl[0];
#pragma unroll
    for (int g = 1; g < G; g++) if (gl[g] > v1) { v1 = gl[g]; i1 = g; }
    int i2 = -1; float v2 = -1e30f;
#pragma unroll
    for (int g = 0; g < G; g++) if (g != i1 && gl[g] > v2) { v2 = gl[g]; i2 = g; }
    float eg = expf(v2 - v1);
    float den = 1.0f / (1.0f + eg);
    float gw_sel[2] = { den, eg * den };
    int g_sel[2] = { i1, i2 };
#pragma unroll
    for (int s = 0; s < 2; s++) {
        int g = g_sel[s]; float gw = gw_sel[s];
        float il[ES];
#pragma unroll
        for (int e = 0; e < ES; e++) il[e] = ilog[((size_t)n * G + g) * ES + e];
        int j1 = 0; float u1 = il[0];
#pragma unroll
        for (int e = 1; e < ES; e++) if (il[e] > u1) { u1 = il[e]; j1 = e; }
        int j2 = -1; float u2 = -1e30f;
#pragma unroll
        for (int e = 0; e < ES; e++) if (e != j1 && il[e] > u2) { u2 = il[e]; j2 = e; }
        float ei = expf(u2 - u1);
        float d2 = 1.0f / (1.0f + ei);
        int ex1 = g * ES + j1, ex2 = g * ES + j2;
        int p1 = atomicAdd(&cnt[ex1], 1);
        toks[(size_t)ex1 * N_TOK + p1] = n * 4 + s * 2;     wgts[(size_t)ex1 * N_TOK + p1] = gw * d2;
        int p2 = atomicAdd(&cnt[ex2], 1);
        toks[(size_t)ex2 * N_TOK + p2] = n * 4 + s * 2 + 1; wgts[(size_t)ex2 * N_TOK + p2] = gw * ei * d2;
    }
}

// ---------------- sparse expert MLPs via bf16 MFMA; expert-major grid; es aliases hs ----------------
// Grid order e-major (e = bid>>7, slot = bid&127): the ~16 active blocks per expert are
// temporally clustered, so each XCD L2 fetches an expert's 0.525MB weight panel ~once
// (vs round-robin e = bid&31 where all 32 experts' panels thrash the 4MB L2).
__global__ __launch_bounds__(512) void k_expert_mfma(
        const __hip_bfloat16* __restrict__ h_normb,
        const short* __restrict__ wB1, const float* __restrict__ eb1,
        const short* __restrict__ wB2, const float* __restrict__ eb2,
        const int* __restrict__ cnt, const int* __restrict__ toks,
        const float* __restrict__ wgts, float* __restrict__ part) {
    const int e = blockIdx.x >> 7;        // expert-major
    const int slot = blockIdx.x & 127;
    const int c = cnt[e];
    const int start = slot * BT;
    if (start >= c) return;
    const int m = min(BT, c - start);

    __shared__ short hs[BT][520];                   // 33.3 KB; es aliases (dead after phase 1)
    short (*es)[264] = (short(*)[264])&hs[0][0];    // 16.9 KB
    __shared__ int   tok_s[BT];
    __shared__ float w_s[BT];

    const int tid = threadIdx.x;
    if (tid < BT) {
        bool ok = tid < m;
        tok_s[tid] = ok ? toks[(size_t)e * N_TOK + start + tid] : 0;
        w_s[tid]   = ok ? wgts[(size_t)e * N_TOK + start + tid] : 0.f;
    }
    __syncthreads();
    for (int idx = tid; idx < BT * 64; idx += 512) {
        int t = idx >> 6, ch = idx & 63;
        uint4 v = make_uint4(0, 0, 0, 0);
        if (t < m) v = *((const uint4*)(h_normb + (size_t)(tok_s[t] >> 2) * DM) + ch);
        *(uint4*)&hs[t][ch * 8] = v;
    }
    __syncthreads();

    const int wave = tid >> 6, lane = tid & 63;
    const int quad = lane >> 4, lm = lane & 15;

    // ---- phase 1: acc = hs @ W1 (reads hs) ----
    const int ng = wave * 2;
    f32x4 acc1[2][2];
#pragma unroll
    for (int a = 0; a < 2; a++)
#pragma unroll
        for (int b = 0; b < 2; b++) acc1[a][b] = (f32x4)(0.f);
    {
        const short* w1e = wB1 + (size_t)e * DM * DE;
        for (int kb = 0; kb < 16; kb++) {
            bf16x8 a0 = *(const bf16x8*)&hs[lm][kb * 32 + quad * 8];
            bf16x8 a1 = *(const bf16x8*)&hs[16 + lm][kb * 32 + quad * 8];
            const short* wp = w1e + ((size_t)kb * 16 + ng) * 512 + lane * 8;
#pragma unroll
            for (int nt = 0; nt < 2; nt++) {
                bf16x8 b = *(const bf16x8*)(wp + nt * 512);
                acc1[0][nt] = MFMA16(a0, b, acc1[0][nt]);
                acc1[1][nt] = MFMA16(a1, b, acc1[1][nt]);
            }
        }
    }
    __syncthreads();   // all waves done reading hs before es overwrite
#pragma unroll
    for (int nt = 0; nt < 2; nt++) {
        int col = (ng + nt) * 16 + lm;
        float b1 = eb1[e * DE + col];
#pragma unroll
        for (int mt = 0; mt < 2; mt++)
#pragma unroll
        for (int r = 0; r < 4; r++) {
            int row = mt * 16 + quad * 4 + r;
            es[row][col] = f2bf(gelu_t(acc1[mt][nt][r] + b1));
        }
    }
    __syncthreads();

    // ---- phase 2: part[tok] = w * (es @ W2 + b2) ----
    {
        const int ng2 = wave * 4;
        f32x4 acc[2][4];
#pragma unroll
        for (int a = 0; a < 2; a++)
#pragma unroll
            for (int b = 0; b < 4; b++) acc[a][b] = (f32x4)(0.f);
        const short* w2e = wB2 + (size_t)e * DE * DM;
        for (int kb = 0; kb < 8; kb++) {
            bf16x8 a0 = *(const bf16x8*)&es[lm][kb * 32 + quad * 8];
            bf16x8 a1 = *(const bf16x8*)&es[16 + lm][kb * 32 + quad * 8];
            const short* wp = w2e + ((size_t)kb * 32 + ng2) * 512 + lane * 8;
#pragma unroll
            for (int nt = 0; nt < 4; nt++) {
                bf16x8 b = *(const bf16x8*)(wp + nt * 512);
                acc[0][nt] = MFMA16(a0, b, acc[0][nt]);
                acc[1][nt] = MFMA16(a1, b, acc[1][nt]);
            }
        }
        const float* b2 = eb2 + (size_t)e * DM;
#pragma unroll
        for (int mt = 0; mt < 2; mt++)
#pragma unroll
        for (int r = 0; r < 4; r++) {
            int row = mt * 16 + quad * 4 + r;
            if (row < m) {
                float w = w_s[row];
                float* prow = part + (size_t)tok_s[row] * DM;
#pragma unroll
                for (int nt = 0; nt < 4; nt++) {
                    int col = (ng2 + nt) * 16 + lm;
                    prow[col] = w * (acc[mt][nt][r] + b2[col]);
                }
            }
        }
    }
}

// ---------------- final reduce: out[n] = sum_s part[n*4+s] ----------------
__global__ void k_reduce(const float* __restrict__ part, float* __restrict__ out) {
    int n = blockIdx.x;
    int j = threadIdx.x; // 0..127
    const float4* p = (const float4*)(part + (size_t)n * 4 * DM);
    float4 a = p[j], b = p[128 + j], c = p[256 + j], d = p[384 + j];
    float4 r = make_float4(a.x + b.x + c.x + d.x, a.y + b.y + c.y + d.y,
                           a.z + b.z + c.z + d.z, a.w + b.w + c.w + d.w);
    ((float4*)(out + (size_t)n * DM))[j] = r;
}

extern "C" void kernel_launch(void* const* d_in, const int* in_sizes, int n_in,
                              void* d_out, int out_size, void* d_ws, size_t ws_size,
                              hipStream_t stream) {
    const float* hidden  = (const float*)d_in[0];
    const float* feat    = (const float*)d_in[1];
    const float* pre_g   = (const float*)d_in[2];
    const float* pre_b   = (const float*)d_in[3];
    const float* rh_g    = (const float*)d_in[4];
    const float* rh_b    = (const float*)d_in[5];
    const float* rh_w1   = (const float*)d_in[6];
    const float* rh_b1   = (const float*)d_in[7];
    const float* rh_w2   = (const float*)d_in[8];
    const float* rh_b2   = (const float*)d_in[9];
    const float* sf_g    = (const float*)d_in[10];
    const float* sf_b    = (const float*)d_in[11];
    const float* sf_w1   = (const float*)d_in[12];
    const float* sf_b1   = (const float*)d_in[13];
    const float* sf_w2   = (const float*)d_in[14];
    const float* sf_b2   = (const float*)d_in[15];
    const float* gln_g   = (const float*)d_in[16];
    const float* gln_b   = (const float*)d_in[17];
    const float* gf_w1   = (const float*)d_in[18];
    const float* gf_b1   = (const float*)d_in[19];
    const float* gf_w2   = (const float*)d_in[20];
    const float* gf_b2   = (const float*)d_in[21];
    const float* pgs_w1  = (const float*)d_in[22];
    const float* pgs_b1  = (const float*)d_in[23];
    const float* pgs_w2  = (const float*)d_in[24];
    const float* pgs_b2  = (const float*)d_in[25];
    const float* ir_w1   = (const float*)d_in[26];
    const float* ir_b1   = (const float*)d_in[27];
    const float* ir_w2   = (const float*)d_in[28];
    const float* ir_b2   = (const float*)d_in[29];
    const float* ex_w1   = (const float*)d_in[30];
    const float* ex_b1   = (const float*)d_in[31];
    const float* ex_w2   = (const float*)d_in[32];
    const float* ex_b2   = (const float*)d_in[33];
    float* out = (float*)d_out;

    // workspace carving (256B-aligned)
    char* w = (char*)d_ws;
    auto alloc = [&](size_t bytes) { void* r = (void*)w; w += (bytes + 255) & ~(size_t)255; return r; };
    __hip_bfloat16* h_normb = (__hip_bfloat16*)alloc((size_t)N_TOK * DM * 2);
    float* h_enc = (float*)alloc((size_t)N_TOK * DH * 4);
    float* s_enc = (float*)alloc((size_t)N_TOK * DH * 4);
    float* g_enc = (float*)alloc((size_t)N_TOK * G * DH * 4);
    float* glog  = (float*)alloc((size_t)N_TOK * G * 4);
    float* ilog  = (float*)alloc((size_t)N_TOK * G * ES * 4);
    float* wgts  = (float*)alloc((size_t)E_EXP * N_TOK * 4);
    short* wB1   = (short*)alloc((size_t)E_EXP * DM * DE * 2);
    short* wB2   = (short*)alloc((size_t)E_EXP * DE * DM * 2);
    short* BpgH  = (short*)alloc((size_t)16 * 8 * 512 * 2);
    short* BpgM  = (short*)alloc((size_t)16 * 8 * 512 * 2);
    short* BpgL  = (short*)alloc((size_t)16 * 8 * 512 * 2);
    short* BirH  = (short*)alloc((size_t)G * 16 * 8 * 512 * 2);
    short* BirM  = (short*)alloc((size_t)G * 16 * 8 * 512 * 2);
    short* BirL  = (short*)alloc((size_t)G * 16 * 8 * 512 * 2);
    short* Brh1H = (short*)alloc((size_t)16 * 8 * 512 * 2);
    short* Brh1M = (short*)alloc((size_t)16 * 8 * 512 * 2);
    short* Brh1L = (short*)alloc((size_t)16 * 8 * 512 * 2);
    short* Brh2H = (short*)alloc((size_t)4 * 8 * 512 * 2);
    short* Brh2M = (short*)alloc((size_t)4 * 8 * 512 * 2);
    short* Brh2L = (short*)alloc((size_t)4 * 8 * 512 * 2);
    short* Bsf1H = (short*)alloc((size_t)4 * 8 * 512 * 2);
    short* Bsf1M = (short*)alloc((size_t)4 * 8 * 512 * 2);
    short* Bsf1L = (short*)alloc((size_t)4 * 8 * 512 * 2);
    short* Bsf2H = (short*)alloc((size_t)4 * 8 * 512 * 2);
    short* Bsf2M = (short*)alloc((size_t)4 * 8 * 512 * 2);
    short* Bsf2L = (short*)alloc((size_t)4 * 8 * 512 * 2);
    short* Bgf1H = (short*)alloc((size_t)G * 1 * 8 * 512 * 2);
    short* Bgf1M = (short*)alloc((size_t)G * 1 * 8 * 512 * 2);
    short* Bgf1L = (short*)alloc((size_t)G * 1 * 8 * 512 * 2);
    short* Bgf2H = (short*)alloc((size_t)G * 4 * 8 * 512 * 2);
    short* Bgf2M = (short*)alloc((size_t)G * 4 * 8 * 512 * 2);
    short* Bgf2L = (short*)alloc((size_t)G * 4 * 8 * 512 * 2);
    int* cnt     = (int*)alloc(E_EXP * 4);
    int* toks    = (int*)alloc((size_t)E_EXP * N_TOK * 4);
    // union region (disjoint live ranges, stream-ordered):
    //   hL   [k_pre -> k_enc_all]          8.4 MB
    //   part [k_expert_mfma -> k_reduce]  33.6 MB
    char* uni   = (char*)alloc((size_t)N_TOK * 4 * DM * 4); // 33.6 MB = max
    float* hL   = (float*)uni;
    float* part = (float*)uni;

    hipMemsetAsync(cnt, 0, E_EXP * sizeof(int), stream);

    // pre-pass: SMALL weight-conversion jobs (212 blocks) + 4096 LN blocks.
    // Expert-weight jobs (ex_w1/ex_w2, 768 blocks) are deferred into k_enc_all.
    ConvJobs J;
    int b0 = 0;
    auto mkjob = [&](int i, const float* s, short* dh, short* dm, short* dl,
                     int KB, int NB, int Kreal, int plain, int nmat) {
        J.j[i] = ConvJob{s, dh, dm, dl, KB, NB, Kreal, plain, b0};
        b0 += KB * nmat;
    };
    mkjob(0, pgs_w1, BpgH, BpgM, BpgL, 16, 8, 512, 0, 1);
    mkjob(1, ir_w1, BirH, BirM, BirL, 16, 8, 512, 0, G);
    mkjob(2, rh_w1, Brh1H, Brh1M, Brh1L, 16, 8, 512, 0, 1);
    mkjob(3, rh_w2, Brh2H, Brh2M, Brh2L, 4, 8, 128, 0, 1);
    mkjob(4, sf_w1, Bsf1H, Bsf1M, Bsf1L, 4, 8, 128, 0, 1);
    mkjob(5, sf_w2, Bsf2H, Bsf2M, Bsf2L, 4, 8, 128, 0, 1);
    mkjob(6, gf_w1, Bgf1H, Bgf1M, Bgf1L, 1, 8, 16, 0, G);
    mkjob(7, gf_w2, Bgf2H, Bgf2M, Bgf2L, 4, 8, 128, 0, G);
    J.j[8].blk0 = 0x7fffffff;   // unused slots never selected
    J.j[9].blk0 = 0x7fffffff;
    k_pre<<<b0 + N_TOK, 256, 0, stream>>>(J, b0, hidden, pre_g, pre_b, rh_g, rh_b, h_normb, hL);

    // expert-weight conversion jobs folded into k_enc_all (bids 0..767)
    ConvJobs2 JE;
    JE.j[0] = ConvJob{ex_w1, wB1, nullptr, nullptr, 16, 16, 512, 1, 0};    // 512 blocks
    JE.j[1] = ConvJob{ex_w2, wB2, nullptr, nullptr, 8, 32, 256, 1, 512};   // 256 blocks

    // fused encoders: exconv(768) + rh(128) + sf(128) + per-(tile,group) genc(1024) = 2048 blocks
    k_enc_all<<<768 + 256 + (N_TOK / 32) * G, 256, 0, stream>>>(
        JE, hL, feat, sf_g, sf_b, gln_g, gln_b,
        Brh1H, Brh1M, Brh1L, rh_b1, Brh2H, Brh2M, Brh2L, rh_b2,
        Bsf1H, Bsf1M, Bsf1L, sf_b1, Bsf2H, Bsf2M, Bsf2L, sf_b2,
        Bgf1H, Bgf1M, Bgf1L, gf_b1, Bgf2H, Bgf2M, Bgf2L, gf_b2,
        h_enc, s_enc, g_enc);

    // router (round-0 verbatim): 64-token tiles, 512 threads, in-kernel A staging
    k_router_mfma<<<(N_TOK / 64) * G, 512, 0, stream>>>(h_enc, s_enc, g_enc,
                                             BpgH, BpgM, BpgL, BirH, BirM, BirL,
                                             pgs_b1, pgs_w2, pgs_b2, ir_b1, ir_w2, ir_b2,
                                             glog, ilog);

    k_topk<<<N_TOK / 256, 256, 0, stream>>>(glog, ilog, cnt, toks, wgts);
    // expert-major 1D grid: bid = e*128 + slot (L2-friendly weight reuse)
    k_expert_mfma<<<(N_TOK / BT) * E_EXP, 512, 0, stream>>>(h_normb, wB1, ex_b1, wB2, ex_b2,
                                                            cnt, toks, wgts, part);
    k_reduce<<<N_TOK, 128, 0, stream>>>(part, out);
}

// Round 10
// 298.004 us; speedup vs baseline: 1.1135x; 1.1135x over previous
//
#include <hip/hip_runtime.h>
#include <hip/hip_bf16.h>
#include <math.h>

#define N_TOK 4096
#define DM 512
#define FDIM 128
#define G 8
#define FG 16
#define DH 128
#define DE 256
#define ES 4
#define E_EXP 32
#define LN_EPS 1e-5f
#define BT 32   // expert token tile (MFMA)

typedef __attribute__((ext_vector_type(8))) short bf16x8;  // 8 bf16 = 4 VGPRs
typedef __attribute__((ext_vector_type(4))) float f32x4;

#define MFMA16(a, b, c) __builtin_amdgcn_mfma_f32_16x16x32_bf16((a), (b), (c), 0, 0, 0)

__device__ __forceinline__ float gelu_t(float x) {
    const float c = 0.7978845608028654f; // sqrt(2/pi)
    float x3 = x * x * x;
    return 0.5f * x * (1.0f + tanhf(c * (x + 0.044715f * x3)));
}

__device__ __forceinline__ short f2bf(float f) {
    __hip_bfloat16 h = __float2bfloat16(f);
    return *reinterpret_cast<short*>(&h);
}
__device__ __forceinline__ float bf2f(short s) {
    __hip_bfloat16 h = *reinterpret_cast<__hip_bfloat16*>(&s);
    return __bfloat162float(h);
}
// exact 3-way split: x == bf2f(h)+bf2f(m)+bf2f(l) bit-exactly for fp32 x
__device__ __forceinline__ void split3(float x, short& h, short& m, short& l) {
    h = f2bf(x);
    float r = x - bf2f(h);   // exact in fp32
    m = f2bf(r);
    float r2 = r - bf2f(m);  // exact; <=6 significant bits remain
    l = f2bf(r2);            // exact
}

// ---------------- weight conversion block body (shared by k_pre and k_enc_all) ----------------
struct ConvJob { const float* src; short* dh; short* dm; short* dl;
                 int KB, NB, Kreal, plain, blk0; };
struct ConvJobs { ConvJob j[10]; };
struct ConvJobs2 { ConvJob j[2]; };

__device__ __forceinline__ void conv_block(const ConvJob jb, int rel) {
    int mat = rel / jb.KB, kb = rel % jb.KB;
    int ncols = jb.NB * 16;
    const float* s = jb.src + (size_t)mat * jb.Kreal * ncols;
    size_t dbase = ((size_t)mat * jb.KB + kb) * jb.NB * 512;
    for (int p = threadIdx.x; p < jb.NB * 64; p += 256) {
        int nb = p >> 6, lane = p & 63;
        int row0 = kb * 32 + ((lane >> 4) << 3);
        int col = nb * 16 + (lane & 15);
        if (jb.plain) {
            union { short sh[8]; uint4 v; } t;
#pragma unroll
            for (int j = 0; j < 8; j++) {
                float x = (row0 + j < jb.Kreal) ? s[(size_t)(row0 + j) * ncols + col] : 0.f;
                t.sh[j] = f2bf(x);
            }
            *(uint4*)&jb.dh[dbase + (size_t)p * 8] = t.v;
        } else {
            union { short sh[8]; uint4 v; } hi, mi, lo;
#pragma unroll
            for (int j = 0; j < 8; j++) {
                float x = (row0 + j < jb.Kreal) ? s[(size_t)(row0 + j) * ncols + col] : 0.f;
                split3(x, hi.sh[j], mi.sh[j], lo.sh[j]);
            }
            *(uint4*)&jb.dh[dbase + (size_t)p * 8] = hi.v;
            *(uint4*)&jb.dm[dbase + (size_t)p * 8] = mi.v;
            *(uint4*)&jb.dl[dbase + (size_t)p * 8] = lo.v;
        }
    }
}

// ---------------- fused pre-pass: cnt-zero + small weight-conversion jobs + LN(hidden) ----------------
__global__ void k_pre(ConvJobs J, int nconv,
                      const float* __restrict__ hidden,
                      const float* __restrict__ pg, const float* __restrict__ pb,
                      const float* __restrict__ rg, const float* __restrict__ rb,
                      __hip_bfloat16* __restrict__ h_normb, float* __restrict__ hL,
                      int* __restrict__ cnt) {
    int b = blockIdx.x;
    if (b == 0 && threadIdx.x < E_EXP) cnt[threadIdx.x] = 0;   // replaces hipMemsetAsync
    if (b >= nconv) {
        // -------- LN of hidden: pre_ln -> h_norm (bf16) and rh_ln -> hL (fp32) --------
        int n = b - nconv;
        int j = threadIdx.x; // 0..255
        const float* x = hidden + (size_t)n * DM;
        float v0 = x[j], v1 = x[j + 256];
        float s = v0 + v1, q = v0 * v0 + v1 * v1;
#pragma unroll
        for (int o = 32; o; o >>= 1) { s += __shfl_down(s, o); q += __shfl_down(q, o); }
        __shared__ float red[8];
        int w = j >> 6;
        if ((j & 63) == 0) { red[w] = s; red[4 + w] = q; }
        __syncthreads();
        float sum = red[0] + red[1] + red[2] + red[3];
        float sq  = red[4] + red[5] + red[6] + red[7];
        float m = sum * (1.0f / DM);
        float var = sq * (1.0f / DM) - m * m;
        float rs = rsqrtf(var + LN_EPS);
        float t0 = (v0 - m) * rs, t1 = (v1 - m) * rs;
        size_t base = (size_t)n * DM;
        h_normb[base + j]       = __float2bfloat16(t0 * pg[j]       + pb[j]);
        h_normb[base + j + 256] = __float2bfloat16(t1 * pg[j + 256] + pb[j + 256]);
        hL[base + j]           = t0 * rg[j]       + rb[j];
        hL[base + j + 256]     = t1 * rg[j + 256] + rb[j + 256];
        return;
    }
    int ji = 0;
#pragma unroll
    for (int i = 1; i < 10; i++) if (b >= J.j[i].blk0) ji = i;
    conv_block(J.j[ji], b - J.j[ji].blk0);
}

// ---------------- 2-layer MLP body via 3-split MFMA: Y = gelu(LN?(X)@W1+b1)@W2+b2 ----------------
template <int KB_TOT, bool DO_LN>
__device__ __forceinline__ void enc2_body(
        int bx, char* smem,
        const float* __restrict__ X,
        const float* __restrict__ lng, const float* __restrict__ lnb,
        const short* __restrict__ W1h, const short* __restrict__ W1m, const short* __restrict__ W1l,
        const float* __restrict__ B1,
        const short* __restrict__ W2h, const short* __restrict__ W2m, const short* __restrict__ W2l,
        const float* __restrict__ B2,
        float* __restrict__ Y) {
    constexpr int K = KB_TOT * 32;
    const int n0 = bx * 32;
    const int tid = threadIdx.x;
    const int wave = tid >> 6, lane = tid & 63;
    const int quad = lane >> 4, lm = lane & 15;
    const int mt = wave & 1;
    const int ngb = (wave >> 1) * 4;   // 4 n-tiles per wave

    short (*Ah)[132] = (short(*)[132])smem;
    short (*Am)[132] = (short(*)[132])(smem + 32 * 132 * 2);
    short (*Al)[132] = (short(*)[132])(smem + 2 * 32 * 132 * 2);

    f32x4 acc[4];
#pragma unroll
    for (int i = 0; i < 4; i++) acc[i] = (f32x4)(0.f);

    if (DO_LN) {
        for (int idx = tid; idx < 1024; idx += 256) {
            int row = idx >> 5, c4 = (idx & 31) * 4;
            float4 v = *(const float4*)&X[(size_t)(n0 + row) * K + c4];
            float s = v.x + v.y + v.z + v.w;
            float q = v.x * v.x + v.y * v.y + v.z * v.z + v.w * v.w;
#pragma unroll
            for (int o = 16; o; o >>= 1) { s += __shfl_xor(s, o); q += __shfl_xor(q, o); }
            float mean = s * (1.0f / 128.0f);
            float var = q * (1.0f / 128.0f) - mean * mean;
            float rs = rsqrtf(var + LN_EPS);
            float xv[4] = {(v.x - mean) * rs * lng[c4 + 0] + lnb[c4 + 0],
                           (v.y - mean) * rs * lng[c4 + 1] + lnb[c4 + 1],
                           (v.z - mean) * rs * lng[c4 + 2] + lnb[c4 + 2],
                           (v.w - mean) * rs * lng[c4 + 3] + lnb[c4 + 3]};
#pragma unroll
            for (int j = 0; j < 4; j++) {
                short h, m, l; split3(xv[j], h, m, l);
                Ah[row][c4 + j] = h; Am[row][c4 + j] = m; Al[row][c4 + j] = l;
            }
        }
        __syncthreads();
#pragma unroll
        for (int kb = 0; kb < KB_TOT; kb++) {
            bf16x8 ah = *(const bf16x8*)&Ah[mt * 16 + lm][kb * 32 + quad * 8];
            bf16x8 am = *(const bf16x8*)&Am[mt * 16 + lm][kb * 32 + quad * 8];
            bf16x8 al = *(const bf16x8*)&Al[mt * 16 + lm][kb * 32 + quad * 8];
#pragma unroll
            for (int nt = 0; nt < 4; nt++) {
                size_t bi = (((size_t)kb * 8 + ngb + nt) * 64 + lane) * 8;
                bf16x8 bh = *(const bf16x8*)&W1h[bi];
                bf16x8 bm = *(const bf16x8*)&W1m[bi];
                bf16x8 bl = *(const bf16x8*)&W1l[bi];
                acc[nt] = MFMA16(al, bh, acc[nt]);
                acc[nt] = MFMA16(am, bm, acc[nt]);
                acc[nt] = MFMA16(ah, bl, acc[nt]);
                acc[nt] = MFMA16(am, bh, acc[nt]);
                acc[nt] = MFMA16(ah, bm, acc[nt]);
                acc[nt] = MFMA16(ah, bh, acc[nt]);
            }
        }
    } else {
        for (int kb = 0; kb < KB_TOT; kb++) {
            const float* xs = X + (size_t)(n0 + mt * 16 + lm) * K + kb * 32 + quad * 8;
            float4 x0 = *(const float4*)xs, x1 = *(const float4*)(xs + 4);
            float xv[8] = {x0.x, x0.y, x0.z, x0.w, x1.x, x1.y, x1.z, x1.w};
            bf16x8 ah, am, al;
#pragma unroll
            for (int j = 0; j < 8; j++) {
                short h, m, l; split3(xv[j], h, m, l);
                ah[j] = h; am[j] = m; al[j] = l;
            }
#pragma unroll
            for (int nt = 0; nt < 4; nt++) {
                size_t bi = (((size_t)kb * 8 + ngb + nt) * 64 + lane) * 8;
                bf16x8 bh = *(const bf16x8*)&W1h[bi];
                bf16x8 bm = *(const bf16x8*)&W1m[bi];
                bf16x8 bl = *(const bf16x8*)&W1l[bi];
                acc[nt] = MFMA16(al, bh, acc[nt]);
                acc[nt] = MFMA16(am, bm, acc[nt]);
                acc[nt] = MFMA16(ah, bl, acc[nt]);
                acc[nt] = MFMA16(am, bh, acc[nt]);
                acc[nt] = MFMA16(ah, bm, acc[nt]);
                acc[nt] = MFMA16(ah, bh, acc[nt]);
            }
        }
    }
    __syncthreads();
#pragma unroll
    for (int nt = 0; nt < 4; nt++) {
        int col = (ngb + nt) * 16 + lm;
        float b1 = B1[col];
#pragma unroll
        for (int r = 0; r < 4; r++) {
            int row = mt * 16 + quad * 4 + r;
            short h, m, l; split3(gelu_t(acc[nt][r] + b1), h, m, l);
            Ah[row][col] = h; Am[row][col] = m; Al[row][col] = l;
        }
    }
    __syncthreads();
    f32x4 acc2[4];
#pragma unroll
    for (int i = 0; i < 4; i++) acc2[i] = (f32x4)(0.f);
#pragma unroll
    for (int kb = 0; kb < 4; kb++) {
        bf16x8 ah = *(const bf16x8*)&Ah[mt * 16 + lm][kb * 32 + quad * 8];
        bf16x8 am = *(const bf16x8*)&Am[mt * 16 + lm][kb * 32 + quad * 8];
        bf16x8 al = *(const bf16x8*)&Al[mt * 16 + lm][kb * 32 + quad * 8];
#pragma unroll
        for (int nt = 0; nt < 4; nt++) {
            size_t bi = (((size_t)kb * 8 + ngb + nt) * 64 + lane) * 8;
            bf16x8 bh = *(const bf16x8*)&W2h[bi];
            bf16x8 bm = *(const bf16x8*)&W2m[bi];
            bf16x8 bl = *(const bf16x8*)&W2l[bi];
            acc2[nt] = MFMA16(al, bh, acc2[nt]);
            acc2[nt] = MFMA16(am, bm, acc2[nt]);
            acc2[nt] = MFMA16(ah, bl, acc2[nt]);
            acc2[nt] = MFMA16(am, bh, acc2[nt]);
            acc2[nt] = MFMA16(ah, bm, acc2[nt]);
            acc2[nt] = MFMA16(ah, bh, acc2[nt]);
        }
    }
#pragma unroll
    for (int nt = 0; nt < 4; nt++) {
        int col = (ngb + nt) * 16 + lm;
        float b2 = B2[col];
#pragma unroll
        for (int r = 0; r < 4; r++) {
            int row = mt * 16 + quad * 4 + r;
            Y[(size_t)(n0 + row) * DH + col] = acc2[nt][r] + b2;
        }
    }
}

// ---------------- single-group encoder body: one (32-token tile, group) per block ----------------
__device__ __forceinline__ void genc_one(
        int bx, int g, char* smem,
        const float* __restrict__ feat,
        const float* __restrict__ gln_g, const float* __restrict__ gln_b,
        const short* __restrict__ W1h, const short* __restrict__ W1m, const short* __restrict__ W1l,
        const float* __restrict__ gb1,
        const short* __restrict__ W2h, const short* __restrict__ W2m, const short* __restrict__ W2l,
        const float* __restrict__ gb2,
        float* __restrict__ g_enc) {
    const int tid = threadIdx.x;
    const int wave = tid >> 6, lane = tid & 63;
    const int quad = lane >> 4, lm = lane & 15;
    const int mt = wave & 1;
    const int ngb = (wave >> 1) * 4;
    const int n0 = bx * 32;

    short (*Ah)[132] = (short(*)[132])smem;
    short (*Am)[132] = (short(*)[132])(smem + 8448);
    short (*Al)[132] = (short(*)[132])(smem + 2 * 8448);

    {
        int t = tid >> 3, sub = tid & 7;
        const float* fr = feat + (size_t)(n0 + t) * FDIM + g * FG;
        float xv[FG];
        float mean = 0.f;
#pragma unroll
        for (int i = 0; i < FG; i++) { xv[i] = fr[i]; mean += xv[i]; }
        mean *= (1.0f / FG);
        float var = 0.f;
#pragma unroll
        for (int i = 0; i < FG; i++) { float d = xv[i] - mean; var += d * d; }
        var *= (1.0f / FG);
        float rs = rsqrtf(var + LN_EPS);
#pragma unroll
        for (int j = 0; j < 2; j++) {
            int i = sub * 2 + j;
            float xn = (xv[i] - mean) * rs * gln_g[g * FG + i] + gln_b[g * FG + i];
            short h, m, l; split3(xn, h, m, l);
            Ah[t][i] = h; Am[t][i] = m; Al[t][i] = l;
            Ah[t][16 + i] = 0; Am[t][16 + i] = 0; Al[t][16 + i] = 0;  // K pad to 32
        }
    }
    __syncthreads();
    f32x4 acc[4];
#pragma unroll
    for (int i = 0; i < 4; i++) acc[i] = (f32x4)(0.f);
    {
        bf16x8 ah = *(const bf16x8*)&Ah[mt * 16 + lm][quad * 8];
        bf16x8 am = *(const bf16x8*)&Am[mt * 16 + lm][quad * 8];
        bf16x8 al = *(const bf16x8*)&Al[mt * 16 + lm][quad * 8];
#pragma unroll
        for (int nt = 0; nt < 4; nt++) {
            size_t bi = (((size_t)g * 8 + ngb + nt) * 64 + lane) * 8;  // KB=1 per mat
            bf16x8 bh = *(const bf16x8*)&W1h[bi];
            bf16x8 bm = *(const bf16x8*)&W1m[bi];
            bf16x8 bl = *(const bf16x8*)&W1l[bi];
            acc[nt] = MFMA16(al, bh, acc[nt]);
            acc[nt] = MFMA16(am, bm, acc[nt]);
            acc[nt] = MFMA16(ah, bl, acc[nt]);
            acc[nt] = MFMA16(am, bh, acc[nt]);
            acc[nt] = MFMA16(ah, bm, acc[nt]);
            acc[nt] = MFMA16(ah, bh, acc[nt]);
        }
    }
    __syncthreads();
#pragma unroll
    for (int nt = 0; nt < 4; nt++) {
        int col = (ngb + nt) * 16 + lm;
        float b1 = gb1[g * DH + col];
#pragma unroll
        for (int r = 0; r < 4; r++) {
            int row = mt * 16 + quad * 4 + r;
            short h, m, l; split3(gelu_t(acc[nt][r] + b1), h, m, l);
            Ah[row][col] = h; Am[row][col] = m; Al[row][col] = l;
        }
    }
    __syncthreads();
    f32x4 acc2[4];
#pragma unroll
    for (int i = 0; i < 4; i++) acc2[i] = (f32x4)(0.f);
#pragma unroll
    for (int kb = 0; kb < 4; kb++) {
        bf16x8 a2h = *(const bf16x8*)&Ah[mt * 16 + lm][kb * 32 + quad * 8];
        bf16x8 a2m = *(const bf16x8*)&Am[mt * 16 + lm][kb * 32 + quad * 8];
        bf16x8 a2l = *(const bf16x8*)&Al[mt * 16 + lm][kb * 32 + quad * 8];
#pragma unroll
        for (int nt = 0; nt < 4; nt++) {
            size_t bi = ((((size_t)g * 4 + kb) * 8 + ngb + nt) * 64 + lane) * 8;
            bf16x8 bh = *(const bf16x8*)&W2h[bi];
            bf16x8 bm = *(const bf16x8*)&W2m[bi];
            bf16x8 bl = *(const bf16x8*)&W2l[bi];
            acc2[nt] = MFMA16(a2l, bh, acc2[nt]);
            acc2[nt] = MFMA16(a2m, bm, acc2[nt]);
            acc2[nt] = MFMA16(a2h, bl, acc2[nt]);
            acc2[nt] = MFMA16(a2m, bh, acc2[nt]);
            acc2[nt] = MFMA16(a2h, bm, acc2[nt]);
            acc2[nt] = MFMA16(a2h, bh, acc2[nt]);
        }
    }
#pragma unroll
    for (int nt = 0; nt < 4; nt++) {
        int col = (ngb + nt) * 16 + lm;
        float b2 = gb2[g * DH + col];
#pragma unroll
        for (int r = 0; r < 4; r++) {
            int row = mt * 16 + quad * 4 + r;
            g_enc[((size_t)(n0 + row) * G + g) * DH + col] = acc2[nt][r] + b2;
        }
    }
}

// ---------------- fused encoder launch: exconv(768) + rh(128) + sf(128) + genc(1024) ----------------
// Expert-weight conversion blocks (bids 0..767) are only needed before k_expert (3 launches
// later) -- folding them here takes them off the serial critical path and overlaps their
// memory traffic with the VALU/MFMA-bound encoder blocks.
__global__ __launch_bounds__(256) void k_enc_all(
        ConvJobs2 JE,
        const float* __restrict__ hL, const float* __restrict__ feat,
        const float* __restrict__ sf_g, const float* __restrict__ sf_b,
        const float* __restrict__ gln_g, const float* __restrict__ gln_b,
        const short* Brh1H, const short* Brh1M, const short* Brh1L, const float* rh_b1,
        const short* Brh2H, const short* Brh2M, const short* Brh2L, const float* rh_b2,
        const short* Bsf1H, const short* Bsf1M, const short* Bsf1L, const float* sf_b1,
        const short* Bsf2H, const short* Bsf2M, const short* Bsf2L, const float* sf_b2,
        const short* Bgf1H, const short* Bgf1M, const short* Bgf1L, const float* gf_b1,
        const short* Bgf2H, const short* Bgf2M, const short* Bgf2L, const float* gf_b2,
        float* __restrict__ h_enc, float* __restrict__ s_enc, float* __restrict__ g_enc) {
    __shared__ __align__(16) char smem[3 * 8448];   // 25.3 KB -> 6 blocks/CU
    int bid = blockIdx.x;
    if (bid < 768) {
        const ConvJob jb = (bid < JE.j[1].blk0) ? JE.j[0] : JE.j[1];
        conv_block(jb, bid - jb.blk0);
        return;
    }
    int b2 = bid - 768;
    if (b2 < 128)
        enc2_body<16, false>(b2, smem, hL, nullptr, nullptr,
                             Brh1H, Brh1M, Brh1L, rh_b1, Brh2H, Brh2M, Brh2L, rh_b2, h_enc);
    else if (b2 < 256)
        enc2_body<4, true>(b2 - 128, smem, feat, sf_g, sf_b,
                           Bsf1H, Bsf1M, Bsf1L, sf_b1, Bsf2H, Bsf2M, Bsf2L, sf_b2, s_enc);
    else {
        int idx = b2 - 256;    // (idx & 7) = group -> XCD affinity for gf weights
        genc_one(idx >> 3, idx & 7, smem, feat, gln_g, gln_b,
                 Bgf1H, Bgf1M, Bgf1L, gf_b1, Bgf2H, Bgf2M, Bgf2L, gf_b2, g_enc);
    }
}

// ---------------- MFMA router v4 (round-0 verbatim): 64 tokens x 1 group, 8 waves ----------------
// Serial epilogue kept intentionally: this exact body compiles to VGPR 64 -> 3 blocks/CU ->
// 54us; every variant (incl. parallel epilogue) pushed VGPR to 120 -> 2 blocks/CU -> 75-105us.
// DO NOT TOUCH.
__global__ __launch_bounds__(512) void k_router_mfma(
        const float* __restrict__ h_enc, const float* __restrict__ s_enc,
        const float* __restrict__ g_enc,
        const short* __restrict__ BpgH, const short* __restrict__ BpgM, const short* __restrict__ BpgL,
        const short* __restrict__ BirH, const short* __restrict__ BirM, const short* __restrict__ BirL,
        const float* __restrict__ pb1, const float* __restrict__ pw2, const float* __restrict__ pb2,
        const float* __restrict__ ib1, const float* __restrict__ iw2, const float* __restrict__ ib2,
        float* __restrict__ glog, float* __restrict__ ilog) {
    const int g = blockIdx.x & 7;       // group -> XCD affinity for B + g_enc
    const int bx = blockIdx.x >> 3;     // 64-token tile (0..63)
    const int n0 = bx * 64;
    const int tid = threadIdx.x;
    const int wave = tid >> 6, lane = tid & 63;
    const int quad = lane >> 4, lm = lane & 15;
    const bool is_pg = wave < 4;
    const int nbase = (wave & 3) * 2;   // 2 n-tiles per wave, 4 waves cover 8
    const short* Bh = is_pg ? BpgH : (BirH + (size_t)g * 65536);
    const short* Bm = is_pg ? BpgM : (BirM + (size_t)g * 65536);
    const short* Bl = is_pg ? BpgL : (BirL + (size_t)g * 65536);

    // LDS: A staging for one 4-kb chunk: [split 3][kbl 4][t16 4][lane 64][8 shorts] = 48 KB.
    // Epilogue (2 x 32x129 fp32 = 33 KB) aliases it after the K-loop.
    __shared__ __align__(16) char smem[49152];

    f32x4 acc[4][2];
#pragma unroll
    for (int mt = 0; mt < 4; mt++)
#pragma unroll
        for (int nt = 0; nt < 2; nt++) acc[mt][nt] = (f32x4)(0.f);

    for (int ch = 0; ch < 4; ch++) {
        __syncthreads();   // previous chunk's LDS reads complete
        // stage chunk: items = (kbl, t16, lane2); split3 from raw encoder fp32
        for (int idx = tid; idx < 1024; idx += 512) {
            int kbl = idx >> 8, rem = idx & 255;
            int t16 = rem >> 6, lane2 = rem & 63;
            int gkb = ch * 4 + kbl;
            size_t loff = (size_t)kbl * 4096 + t16 * 1024 + (size_t)lane2 * 16;
            int n = n0 + t16 * 16 + (lane2 & 15);
            int csub = (lane2 >> 4) * 8;
            float xv[8];
            if (gkb < 8) {
                // k in [0,256) = [h_enc | s_enc]
                int c0 = gkb * 32 + csub;
                const float* src = (c0 < 128) ? (h_enc + (size_t)n * DH + c0)
                                              : (s_enc + (size_t)n * DH + (c0 - 128));
                float4 x0 = *(const float4*)src, x1 = *(const float4*)(src + 4);
                xv[0]=x0.x; xv[1]=x0.y; xv[2]=x0.z; xv[3]=x0.w;
                xv[4]=x1.x; xv[5]=x1.y; xv[6]=x1.z; xv[7]=x1.w;
            } else {
                // k in [256,512) = [g_enc | h_enc*g_enc]
                int c0 = (gkb - 8) * 32 + csub;
                if (c0 < 128) {
                    const float* gs = g_enc + ((size_t)n * G + g) * DH + c0;
                    float4 x0 = *(const float4*)gs, x1 = *(const float4*)(gs + 4);
                    xv[0]=x0.x; xv[1]=x0.y; xv[2]=x0.z; xv[3]=x0.w;
                    xv[4]=x1.x; xv[5]=x1.y; xv[6]=x1.z; xv[7]=x1.w;
                } else {
                    int c = c0 - 128;
                    const float* gs = g_enc + ((size_t)n * G + g) * DH + c;
                    const float* hsrc = h_enc + (size_t)n * DH + c;
                    float4 g0 = *(const float4*)gs, g1 = *(const float4*)(gs + 4);
                    float4 h0 = *(const float4*)hsrc, h1 = *(const float4*)(hsrc + 4);
                    xv[0]=h0.x*g0.x; xv[1]=h0.y*g0.y; xv[2]=h0.z*g0.z; xv[3]=h0.w*g0.w;
                    xv[4]=h1.x*g1.x; xv[5]=h1.y*g1.y; xv[6]=h1.z*g1.z; xv[7]=h1.w*g1.w;
                }
            }
            union { short sh[8]; uint4 v; } hi, mi, lo;
#pragma unroll
            for (int j = 0; j < 8; j++) split3(xv[j], hi.sh[j], mi.sh[j], lo.sh[j]);
            *(uint4*)(smem + loff)         = hi.v;
            *(uint4*)(smem + 16384 + loff) = mi.v;
            *(uint4*)(smem + 32768 + loff) = lo.v;
        }
        __syncthreads();
        // compute chunk
#pragma unroll
        for (int kbl = 0; kbl < 4; kbl++) {
            int kb = ch * 4 + kbl;
            bf16x8 Ahf[4], Amf[4], Alf[4];
#pragma unroll
            for (int mt = 0; mt < 4; mt++) {
                size_t loff = (size_t)kbl * 4096 + mt * 1024 + (size_t)lane * 16;
                Ahf[mt] = *(const bf16x8*)(smem + loff);
                Amf[mt] = *(const bf16x8*)(smem + 16384 + loff);
                Alf[mt] = *(const bf16x8*)(smem + 32768 + loff);
            }
#pragma unroll
            for (int nt = 0; nt < 2; nt++) {
                int nb = nbase + nt;
                size_t bi = (((size_t)kb * 8 + nb) * 64 + lane) * 8;
                bf16x8 bh = *(const bf16x8*)&Bh[bi];
                bf16x8 bm = *(const bf16x8*)&Bm[bi];
                bf16x8 bl = *(const bf16x8*)&Bl[bi];
#pragma unroll
                for (int mt = 0; mt < 4; mt++) {
                    acc[mt][nt] = MFMA16(Alf[mt], bh, acc[mt][nt]);
                    acc[mt][nt] = MFMA16(Amf[mt], bm, acc[mt][nt]);
                    acc[mt][nt] = MFMA16(Ahf[mt], bl, acc[mt][nt]);
                    acc[mt][nt] = MFMA16(Amf[mt], bh, acc[mt][nt]);
                    acc[mt][nt] = MFMA16(Ahf[mt], bm, acc[mt][nt]);
                    acc[mt][nt] = MFMA16(Ahf[mt], bh, acc[mt][nt]);
                }
            }
        }
    }

    // epilogue: two 32-row halves reusing staging LDS (ph 32x129 + ih 32x129 = 33 KB)
    float (*ph)[129] = (float(*)[129])smem;
    float (*ih)[129] = (float(*)[129])(smem + 32 * 129 * 4);
    for (int h = 0; h < 2; h++) {
        __syncthreads();   // h=0: K-loop LDS reads done; h=1: prev half's logit reads done
#pragma unroll
        for (int mi = 0; mi < 2; mi++) {
            int mt = 2 * h + mi;
#pragma unroll
            for (int nt = 0; nt < 2; nt++) {
                int col = (nbase + nt) * 16 + lm;
                float b1 = is_pg ? pb1[col] : ib1[g * DH + col];
                float* dst = is_pg ? &ph[0][0] : &ih[0][0];
#pragma unroll
                for (int r = 0; r < 4; r++) {
                    int row = mi * 16 + quad * 4 + r;
                    dst[row * 129 + col] = gelu_t(acc[mt][nt][r] + b1);
                }
            }
        }
        __syncthreads();
        if (tid < 32) {
            float s = pb2[0];
            for (int i = 0; i < DH; i++) s += ph[tid][i] * pw2[i];
            glog[(size_t)(n0 + h * 32 + tid) * G + g] = s; // TEMP = 1.0
        } else if (tid >= 128 && tid < 256) {
            int t = (tid - 128) >> 2, e = (tid - 128) & 3;
            float s = ib2[g * ES + e];
            const float* w = iw2 + (size_t)g * DH * ES;
            for (int i = 0; i < DH; i++) s += ih[t][i] * w[i * ES + e];
            ilog[((size_t)(n0 + h * 32 + t) * G + g) * ES + e] = s;
        }
    }
}

// ---------------- top-k softmax + dispatch to per-expert lists ----------------
__global__ void k_topk(const float* __restrict__ glog, const float* __restrict__ ilog,
                       int* __restrict__ cnt, int* __restrict__ toks, float* __restrict__ wgts) {
    int n = blockIdx.x * blockDim.x + threadIdx.x;
    if (n >= N_TOK) return;
    float gl[G];
#pragma unroll
    for (int g = 0; g < G; g++) gl[g] = glog[(size_t)n * G + g];
    int i1 = 0; float v1 = gl[0];
#pragma unroll
    for (int g = 1; g < G; g++) if (gl[g] > v1) { v1 = gl[g]; i1 = g; }
    int i2 = -1; float v2 = -1e30f;
#pragma unroll
    for (int g = 0; g < G; g++) if (g != i1 && gl[g] > v2) { v2 = gl[g]; i2 = g; }
    float eg = expf(v2 - v1);
    float den = 1.0f / (1.0f + eg);
    float gw_sel[2] = { den, eg * den };
    int g_sel[2] = { i1, i2 };
#pragma unroll
    for (int s = 0; s < 2; s++) {
        int g = g_sel[s]; float gw = gw_sel[s];
        float il[ES];
#pragma unroll
        for (int e = 0; e < ES; e++) il[e] = ilog[((size_t)n * G + g) * ES + e];
        int j1 = 0; float u1 = il[0];
#pragma unroll
        for (int e = 1; e < ES; e++) if (il[e] > u1) { u1 = il[e]; j1 = e; }
        int j2 = -1; float u2 = -1e30f;
#pragma unroll
        for (int e = 0; e < ES; e++) if (e != j1 && il[e] > u2) { u2 = il[e]; j2 = e; }
        float ei = expf(u2 - u1);
        float d2 = 1.0f / (1.0f + ei);
        int ex1 = g * ES + j1, ex2 = g * ES + j2;
        int p1 = atomicAdd(&cnt[ex1], 1);
        toks[(size_t)ex1 * N_TOK + p1] = n * 4 + s * 2;     wgts[(size_t)ex1 * N_TOK + p1] = gw * d2;
        int p2 = atomicAdd(&cnt[ex2], 1);
        toks[(size_t)ex2 * N_TOK + p2] = n * 4 + s * 2 + 1; wgts[(size_t)ex2 * N_TOK + p2] = gw * ei * d2;
    }
}

// ---------------- sparse expert MLPs via bf16 MFMA; XCD-affine slot-major grid ----------------
// e = bid & 31 with block->XCD = bid % 8 puts ALL blocks of expert e on XCD (e % 8):
// each XCD hosts 4 experts' weight panels = 2.1 MB, fitting its 4 MB L2. (Round-9's
// e-major order spread panels across all XCDs: FETCH 78 MB, 2x slower. DO NOT REORDER.)
__global__ __launch_bounds__(512) void k_expert_mfma(
        const __hip_bfloat16* __restrict__ h_normb,
        const short* __restrict__ wB1, const float* __restrict__ eb1,
        const short* __restrict__ wB2, const float* __restrict__ eb2,
        const int* __restrict__ cnt, const int* __restrict__ toks,
        const float* __restrict__ wgts, float* __restrict__ part) {
    const int e = blockIdx.x & 31;
    const int slot = blockIdx.x >> 5;
    const int c = cnt[e];
    const int start = slot * BT;
    if (start >= c) return;
    const int m = min(BT, c - start);

    __shared__ short hs[BT][520];                   // 33.3 KB; es aliases (dead after phase 1)
    short (*es)[264] = (short(*)[264])&hs[0][0];    // 16.9 KB
    __shared__ int   tok_s[BT];
    __shared__ float w_s[BT];

    const int tid = threadIdx.x;
    if (tid < BT) {
        bool ok = tid < m;
        tok_s[tid] = ok ? toks[(size_t)e * N_TOK + start + tid] : 0;
        w_s[tid]   = ok ? wgts[(size_t)e * N_TOK + start + tid] : 0.f;
    }
    __syncthreads();
    for (int idx = tid; idx < BT * 64; idx += 512) {
        int t = idx >> 6, ch = idx & 63;
        uint4 v = make_uint4(0, 0, 0, 0);
        if (t < m) v = *((const uint4*)(h_normb + (size_t)(tok_s[t] >> 2) * DM) + ch);
        *(uint4*)&hs[t][ch * 8] = v;
    }
    __syncthreads();

    const int wave = tid >> 6, lane = tid & 63;
    const int quad = lane >> 4, lm = lane & 15;

    // ---- phase 1: acc = hs @ W1 (reads hs) ----
    const int ng = wave * 2;
    f32x4 acc1[2][2];
#pragma unroll
    for (int a = 0; a < 2; a++)
#pragma unroll
        for (int b = 0; b < 2; b++) acc1[a][b] = (f32x4)(0.f);
    {
        const short* w1e = wB1 + (size_t)e * DM * DE;
        for (int kb = 0; kb < 16; kb++) {
            bf16x8 a0 = *(const bf16x8*)&hs[lm][kb * 32 + quad * 8];
            bf16x8 a1 = *(const bf16x8*)&hs[16 + lm][kb * 32 + quad * 8];
            const short* wp = w1e + ((size_t)kb * 16 + ng) * 512 + lane * 8;
#pragma unroll
            for (int nt = 0; nt < 2; nt++) {
                bf16x8 b = *(const bf16x8*)(wp + nt * 512);
                acc1[0][nt] = MFMA16(a0, b, acc1[0][nt]);
                acc1[1][nt] = MFMA16(a1, b, acc1[1][nt]);
            }
        }
    }
    __syncthreads();   // all waves done reading hs before es overwrite
#pragma unroll
    for (int nt = 0; nt < 2; nt++) {
        int col = (ng + nt) * 16 + lm;
        float b1 = eb1[e * DE + col];
#pragma unroll
        for (int mt = 0; mt < 2; mt++)
#pragma unroll
        for (int r = 0; r < 4; r++) {
            int row = mt * 16 + quad * 4 + r;
            es[row][col] = f2bf(gelu_t(acc1[mt][nt][r] + b1));
        }
    }
    __syncthreads();

    // ---- phase 2: part[tok] = w * (es @ W2 + b2) ----
    {
        const int ng2 = wave * 4;
        f32x4 acc[2][4];
#pragma unroll
        for (int a = 0; a < 2; a++)
#pragma unroll
            for (int b = 0; b < 4; b++) acc[a][b] = (f32x4)(0.f);
        const short* w2e = wB2 + (size_t)e * DE * DM;
        for (int kb = 0; kb < 8; kb++) {
            bf16x8 a0 = *(const bf16x8*)&es[lm][kb * 32 + quad * 8];
            bf16x8 a1 = *(const bf16x8*)&es[16 + lm][kb * 32 + quad * 8];
            const short* wp = w2e + ((size_t)kb * 32 + ng2) * 512 + lane * 8;
#pragma unroll
            for (int nt = 0; nt < 4; nt++) {
                bf16x8 b = *(const bf16x8*)(wp + nt * 512);
                acc[0][nt] = MFMA16(a0, b, acc[0][nt]);
                acc[1][nt] = MFMA16(a1, b, acc[1][nt]);
            }
        }
        const float* b2 = eb2 + (size_t)e * DM;
#pragma unroll
        for (int mt = 0; mt < 2; mt++)
#pragma unroll
        for (int r = 0; r < 4; r++) {
            int row = mt * 16 + quad * 4 + r;
            if (row < m) {
                float w = w_s[row];
                float* prow = part + (size_t)tok_s[row] * DM;
#pragma unroll
                for (int nt = 0; nt < 4; nt++) {
                    int col = (ng2 + nt) * 16 + lm;
                    prow[col] = w * (acc[mt][nt][r] + b2[col]);
                }
            }
        }
    }
}

// ---------------- final reduce: out[n] = sum_s part[n*4+s] ----------------
__global__ void k_reduce(const float* __restrict__ part, float* __restrict__ out) {
    int n = blockIdx.x;
    int j = threadIdx.x; // 0..127
    const float4* p = (const float4*)(part + (size_t)n * 4 * DM);
    float4 a = p[j], b = p[128 + j], c = p[256 + j], d = p[384 + j];
    float4 r = make_float4(a.x + b.x + c.x + d.x, a.y + b.y + c.y + d.y,
                           a.z + b.z + c.z + d.z, a.w + b.w + c.w + d.w);
    ((float4*)(out + (size_t)n * DM))[j] = r;
}

extern "C" void kernel_launch(void* const* d_in, const int* in_sizes, int n_in,
                              void* d_out, int out_size, void* d_ws, size_t ws_size,
                              hipStream_t stream) {
    const float* hidden  = (const float*)d_in[0];
    const float* feat    = (const float*)d_in[1];
    const float* pre_g   = (const float*)d_in[2];
    const float* pre_b   = (const float*)d_in[3];
    const float* rh_g    = (const float*)d_in[4];
    const float* rh_b    = (const float*)d_in[5];
    const float* rh_w1   = (const float*)d_in[6];
    const float* rh_b1   = (const float*)d_in[7];
    const float* rh_w2   = (const float*)d_in[8];
    const float* rh_b2   = (const float*)d_in[9];
    const float* sf_g    = (const float*)d_in[10];
    const float* sf_b    = (const float*)d_in[11];
    const float* sf_w1   = (const float*)d_in[12];
    const float* sf_b1   = (const float*)d_in[13];
    const float* sf_w2   = (const float*)d_in[14];
    const float* sf_b2   = (const float*)d_in[15];
    const float* gln_g   = (const float*)d_in[16];
    const float* gln_b   = (const float*)d_in[17];
    const float* gf_w1   = (const float*)d_in[18];
    const float* gf_b1   = (const float*)d_in[19];
    const float* gf_w2   = (const float*)d_in[20];
    const float* gf_b2   = (const float*)d_in[21];
    const float* pgs_w1  = (const float*)d_in[22];
    const float* pgs_b1  = (const float*)d_in[23];
    const float* pgs_w2  = (const float*)d_in[24];
    const float* pgs_b2  = (const float*)d_in[25];
    const float* ir_w1   = (const float*)d_in[26];
    const float* ir_b1   = (const float*)d_in[27];
    const float* ir_w2   = (const float*)d_in[28];
    const float* ir_b2   = (const float*)d_in[29];
    const float* ex_w1   = (const float*)d_in[30];
    const float* ex_b1   = (const float*)d_in[31];
    const float* ex_w2   = (const float*)d_in[32];
    const float* ex_b2   = (const float*)d_in[33];
    float* out = (float*)d_out;

    // workspace carving (256B-aligned)
    char* w = (char*)d_ws;
    auto alloc = [&](size_t bytes) { void* r = (void*)w; w += (bytes + 255) & ~(size_t)255; return r; };
    __hip_bfloat16* h_normb = (__hip_bfloat16*)alloc((size_t)N_TOK * DM * 2);
    float* h_enc = (float*)alloc((size_t)N_TOK * DH * 4);
    float* s_enc = (float*)alloc((size_t)N_TOK * DH * 4);
    float* g_enc = (float*)alloc((size_t)N_TOK * G * DH * 4);
    float* glog  = (float*)alloc((size_t)N_TOK * G * 4);
    float* ilog  = (float*)alloc((size_t)N_TOK * G * ES * 4);
    float* wgts  = (float*)alloc((size_t)E_EXP * N_TOK * 4);
    short* wB1   = (short*)alloc((size_t)E_EXP * DM * DE * 2);
    short* wB2   = (short*)alloc((size_t)E_EXP * DE * DM * 2);
    short* BpgH  = (short*)alloc((size_t)16 * 8 * 512 * 2);
    short* BpgM  = (short*)alloc((size_t)16 * 8 * 512 * 2);
    short* BpgL  = (short*)alloc((size_t)16 * 8 * 512 * 2);
    short* BirH  = (short*)alloc((size_t)G * 16 * 8 * 512 * 2);
    short* BirM  = (short*)alloc((size_t)G * 16 * 8 * 512 * 2);
    short* BirL  = (short*)alloc((size_t)G * 16 * 8 * 512 * 2);
    short* Brh1H = (short*)alloc((size_t)16 * 8 * 512 * 2);
    short* Brh1M = (short*)alloc((size_t)16 * 8 * 512 * 2);
    short* Brh1L = (short*)alloc((size_t)16 * 8 * 512 * 2);
    short* Brh2H = (short*)alloc((size_t)4 * 8 * 512 * 2);
    short* Brh2M = (short*)alloc((size_t)4 * 8 * 512 * 2);
    short* Brh2L = (short*)alloc((size_t)4 * 8 * 512 * 2);
    short* Bsf1H = (short*)alloc((size_t)4 * 8 * 512 * 2);
    short* Bsf1M = (short*)alloc((size_t)4 * 8 * 512 * 2);
    short* Bsf1L = (short*)alloc((size_t)4 * 8 * 512 * 2);
    short* Bsf2H = (short*)alloc((size_t)4 * 8 * 512 * 2);
    short* Bsf2M = (short*)alloc((size_t)4 * 8 * 512 * 2);
    short* Bsf2L = (short*)alloc((size_t)4 * 8 * 512 * 2);
    short* Bgf1H = (short*)alloc((size_t)G * 1 * 8 * 512 * 2);
    short* Bgf1M = (short*)alloc((size_t)G * 1 * 8 * 512 * 2);
    short* Bgf1L = (short*)alloc((size_t)G * 1 * 8 * 512 * 2);
    short* Bgf2H = (short*)alloc((size_t)G * 4 * 8 * 512 * 2);
    short* Bgf2M = (short*)alloc((size_t)G * 4 * 8 * 512 * 2);
    short* Bgf2L = (short*)alloc((size_t)G * 4 * 8 * 512 * 2);
    int* cnt     = (int*)alloc(E_EXP * 4);
    int* toks    = (int*)alloc((size_t)E_EXP * N_TOK * 4);
    // union region (disjoint live ranges, stream-ordered):
    //   hL   [k_pre -> k_enc_all]          8.4 MB
    //   part [k_expert_mfma -> k_reduce]  33.6 MB
    char* uni   = (char*)alloc((size_t)N_TOK * 4 * DM * 4); // 33.6 MB = max
    float* hL   = (float*)uni;
    float* part = (float*)uni;

    // pre-pass: cnt zeroing + SMALL weight-conversion jobs (212 blocks) + 4096 LN blocks.
    // Expert-weight jobs (ex_w1/ex_w2, 768 blocks) are deferred into k_enc_all.
    ConvJobs J;
    int b0 = 0;
    auto mkjob = [&](int i, const float* s, short* dh, short* dm, short* dl,
                     int KB, int NB, int Kreal, int plain, int nmat) {
        J.j[i] = ConvJob{s, dh, dm, dl, KB, NB, Kreal, plain, b0};
        b0 += KB * nmat;
    };
    mkjob(0, pgs_w1, BpgH, BpgM, BpgL, 16, 8, 512, 0, 1);
    mkjob(1, ir_w1, BirH, BirM, BirL, 16, 8, 512, 0, G);
    mkjob(2, rh_w1, Brh1H, Brh1M, Brh1L, 16, 8, 512, 0, 1);
    mkjob(3, rh_w2, Brh2H, Brh2M, Brh2L, 4, 8, 128, 0, 1);
    mkjob(4, sf_w1, Bsf1H, Bsf1M, Bsf1L, 4, 8, 128, 0, 1);
    mkjob(5, sf_w2, Bsf2H, Bsf2M, Bsf2L, 4, 8, 128, 0, 1);
    mkjob(6, gf_w1, Bgf1H, Bgf1M, Bgf1L, 1, 8, 16, 0, G);
    mkjob(7, gf_w2, Bgf2H, Bgf2M, Bgf2L, 4, 8, 128, 0, G);
    J.j[8].blk0 = 0x7fffffff;   // unused slots never selected
    J.j[9].blk0 = 0x7fffffff;
    k_pre<<<b0 + N_TOK, 256, 0, stream>>>(J, b0, hidden, pre_g, pre_b, rh_g, rh_b,
                                          h_normb, hL, cnt);

    // expert-weight conversion jobs folded into k_enc_all (bids 0..767)
    ConvJobs2 JE;
    JE.j[0] = ConvJob{ex_w1, wB1, nullptr, nullptr, 16, 16, 512, 1, 0};    // 512 blocks
    JE.j[1] = ConvJob{ex_w2, wB2, nullptr, nullptr, 8, 32, 256, 1, 512};   // 256 blocks

    // fused encoders: exconv(768) + rh(128) + sf(128) + per-(tile,group) genc(1024) = 2048 blocks
    k_enc_all<<<768 + 256 + (N_TOK / 32) * G, 256, 0, stream>>>(
        JE, hL, feat, sf_g, sf_b, gln_g, gln_b,
        Brh1H, Brh1M, Brh1L, rh_b1, Brh2H, Brh2M, Brh2L, rh_b2,
        Bsf1H, Bsf1M, Bsf1L, sf_b1, Bsf2H, Bsf2M, Bsf2L, sf_b2,
        Bgf1H, Bgf1M, Bgf1L, gf_b1, Bgf2H, Bgf2M, Bgf2L, gf_b2,
        h_enc, s_enc, g_enc);

    // router (round-0 verbatim): 64-token tiles, 512 threads, in-kernel A staging
    k_router_mfma<<<(N_TOK / 64) * G, 512, 0, stream>>>(h_enc, s_enc, g_enc,
                                             BpgH, BpgM, BpgL, BirH, BirM, BirL,
                                             pgs_b1, pgs_w2, pgs_b2, ir_b1, ir_w2, ir_b2,
                                             glog, ilog);

    k_topk<<<N_TOK / 256, 256, 0, stream>>>(glog, ilog, cnt, toks, wgts);
    // XCD-affine slot-major 1D grid: bid = slot*32 + e  (expert e -> XCD e%8)
    k_expert_mfma<<<(N_TOK / BT) * E_EXP, 512, 0, stream>>>(h_normb, wB1, ex_b1, wB2, ex_b2,
                                                            cnt, toks, wgts, part);
    k_reduce<<<N_TOK, 128, 0, stream>>>(part, out);
}